// Round 7
// baseline (999.755 us; speedup 1.0000x reference)
//
#include <hip/hip_runtime.h>

#define H 128
#define D 2
#define T_OBS 20
#define BATCH 16384
#define PRED 30
#define M 32          // batch rows per block (two 16-row halves, one per wave-group)
#define NTH 1024      // 16 waves: wave wv -> mh = wv>>3 (row half), unit group wv&7
#define HP 136        // padded fp16 h-row stride (272 B, 16B-aligned)
#define FP 132        // padded f32 row stride
#define LN_EPS 1e-5f

typedef __attribute__((ext_vector_type(8))) _Float16 half8_t;
typedef __attribute__((ext_vector_type(4))) float float4_t;

__device__ __forceinline__ float fast_rcp(float x){ return __builtin_amdgcn_rcpf(x); }
__device__ __forceinline__ float sig_f(float x){ return fast_rcp(1.f + __expf(-x)); }
__device__ __forceinline__ float tanh_f(float x){ return 1.f - 2.f*fast_rcp(__expf(2.f*x)+1.f); }

// Per-phase per-wave constants: B-fragments for one 16-unit column group, 4 gates.
// bw[g][ks] = 4*4*4 = 64 VGPRs; with acc[4] (16 AGPR) total ~105+16 < 128.
struct PhaseConsts {
  half8_t bw[4][4];
  float bs[4], w0[4], w1[4];
};

__device__ __forceinline__ void load_phase(PhaseConsts& P, const float* __restrict__ Whh,
                                           const float* __restrict__ Wih,
                                           const float* __restrict__ bih,
                                           const float* __restrict__ bhh,
                                           int wvu, int l15, int q){
#pragma unroll
  for(int g=0; g<4; g++){
    const int n = g*H + 16*wvu + l15;
    P.bs[g] = bih[n] + bhh[n];
    P.w0[g] = Wih[n*D + 0];
    P.w1[g] = Wih[n*D + 1];
#pragma unroll
    for(int ks=0; ks<4; ks++){
      const float* p = Whh + (size_t)n*H + ks*32 + q*8;  // B[k][n]=Whh[n][k]
      float4 a = *(const float4*)p;
      float4 b = *(const float4*)(p+4);
      half8_t f;
      f[0]=(_Float16)a.x; f[1]=(_Float16)a.y; f[2]=(_Float16)a.z; f[3]=(_Float16)a.w;
      f[4]=(_Float16)b.x; f[5]=(_Float16)b.y; f[6]=(_Float16)b.z; f[7]=(_Float16)b.w;
      P.bw[g][ks] = f;
    }
  }
}

// Decoder variant: fold the FC feedback into the recurrent matrix.
//   Wcomb[n][k] = Whh[n][k] + Wih[n][0]*Wfc[0][k] + Wih[n][1]*Wfc[1][k]
//   b'[n]      = bih[n]+bhh[n] + Wih[n][0]*bfc[0] + Wih[n][1]*bfc[1]
// Then for t>=1: gates = Wcomb @ h + b'  (no x-path, no fc on critical path).
// Step 0 uses the fp32 x-path with dx = x0 - (Wfc@h0 + bfc).
__device__ __forceinline__ void load_phase_dec(PhaseConsts& P, const float* __restrict__ Whh,
                                               const float* __restrict__ Wih,
                                               const float* __restrict__ bih,
                                               const float* __restrict__ bhh,
                                               const float* __restrict__ Wfc,
                                               const float* __restrict__ bfc,
                                               int wvu, int l15, int q){
#pragma unroll
  for(int g=0; g<4; g++){
    const int n = g*H + 16*wvu + l15;
    const float wi0 = Wih[n*D + 0];
    const float wi1 = Wih[n*D + 1];
    P.bs[g] = bih[n] + bhh[n] + wi0*bfc[0] + wi1*bfc[1];
    P.w0[g] = wi0;
    P.w1[g] = wi1;
#pragma unroll
    for(int ks=0; ks<4; ks++){
      const float* p  = Whh + (size_t)n*H + ks*32 + q*8;   // Whh[n][k..k+7]
      const float* f0 = Wfc + 0*H + ks*32 + q*8;           // Wfc[0][k..k+7]
      const float* f1 = Wfc + 1*H + ks*32 + q*8;           // Wfc[1][k..k+7]
      half8_t f;
#pragma unroll
      for(int j=0;j<8;j++){
        f[j] = (_Float16)(p[j] + wi0*f0[j] + wi1*f1[j]);   // fold in fp32, round once
      }
      P.bw[g][ks] = f;
    }
  }
}

// One LSTM cell step. Each wave handles its 16-row half (rows mrow0..mrow0+15)
// for its 16-unit group. h read from hsh[cur], x from xsrc[32][2] (when HASX),
// new h written to hsh[cur^1]. c per-lane fp32 (4 rows). One barrier.
template<bool HASX>
__device__ __forceinline__ void cell_step(_Float16 (*hsh)[M][HP], int cur,
                                          const float* __restrict__ xsrc,
                                          const PhaseConsts& P, float (&c)[4],
                                          int mrow0, int arow, int u, int l15, int q){
  float4_t acc[4];
  if constexpr (HASX){
    float x0[4], x1[4];
#pragma unroll
    for(int r=0; r<4; r++){
      x0[r] = xsrc[(mrow0 + 4*q+r)*2 + 0];
      x1[r] = xsrc[(mrow0 + 4*q+r)*2 + 1];
    }
#pragma unroll
    for(int g=0; g<4; g++)
#pragma unroll
      for(int r=0; r<4; r++)
        acc[g][r] = fmaf(P.w1[g], x1[r], fmaf(P.w0[g], x0[r], P.bs[g]));
  } else {
#pragma unroll
    for(int g=0; g<4; g++)
#pragma unroll
      for(int r=0; r<4; r++)
        acc[g][r] = P.bs[g];
  }

#pragma unroll
  for(int ks=0; ks<4; ks++){
    const half8_t a = *(const half8_t*)&hsh[cur][arow][ks*32 + q*8];
#pragma unroll
    for(int g=0; g<4; g++){
      acc[g] = __builtin_amdgcn_mfma_f32_16x16x32_f16(a, P.bw[g][ks], acc[g], 0,0,0);
    }
  }
  const int nxt = cur ^ 1;
#pragma unroll
  for(int r=0; r<4; r++){
    const float iv = sig_f(acc[0][r]);
    const float fv = sig_f(acc[1][r]);
    const float gv = tanh_f(acc[2][r]);
    const float ov = sig_f(acc[3][r]);
    const float cc = fmaf(fv, c[r], iv*gv);
    c[r] = cc;
    const float hv = ov * tanh_f(cc);
    hsh[nxt][mrow0 + 4*q + r][u] = (_Float16)hv;
  }
  __syncthreads();
}

// LayerNorm over 128 units for 32 rows; threads 0..511, 16 threads/row.
__device__ __forceinline__ void layernorm32(const float (*src)[FP], float (*dst)[FP],
                                            const float* __restrict__ g,
                                            const float* __restrict__ b, int tid){
  if(tid >= 512) return;
  const int m = tid >> 4, sub = tid & 15;
  float v[8];
  float s = 0.f, s2 = 0.f;
#pragma unroll
  for(int j=0;j<8;j++){ v[j] = src[m][sub*8+j]; s += v[j]; s2 = fmaf(v[j], v[j], s2); }
#pragma unroll
  for(int msk=1; msk<16; msk<<=1){ s += __shfl_xor(s, msk, 64); s2 += __shfl_xor(s2, msk, 64); }
  const float mean = s * (1.f/H);
  const float var  = s2 * (1.f/H) - mean*mean;
  const float inv  = rsqrtf(var + LN_EPS);
#pragma unroll
  for(int j=0;j<8;j++){
    const int u = sub*8+j;
    dst[m][u] = fmaf((v[j]-mean)*inv, g[u], b[u]);
  }
}

// Output-only FC: cs = h @ Wfc^T + bfc from the fp16 plane; writes global out ONLY.
// No barrier needed: reads of hb stay race-free until the buffer is rewritten two
// cell-steps later (each cell step ends in a barrier). Threads 0..511 (32 rows).
__device__ __forceinline__ void fc_out(const _Float16 (*hb)[HP], const float (*wfc)[H],
                                       const float* __restrict__ bfcs,
                                       float* __restrict__ gout, int row0, int tid){
  if(tid >= 512) return;
  const int m = tid >> 4, d = (tid >> 3) & 1, ch = tid & 7;
  const _Float16* hp = &hb[m][ch*16];
  float s = 0.f;
#pragma unroll
  for(int j=0;j<16;j++) s = fmaf((float)hp[j], wfc[d][ch*16+j], s);
  s += __shfl_xor(s, 1, 64); s += __shfl_xor(s, 2, 64); s += __shfl_xor(s, 4, 64);
  if(ch == 0){
    gout[(size_t)(row0+m)*D + d] = s + bfcs[d];
  }
}

// Step-0 delta: xb[m][d] = xlast[m][d] - (Wfc@h0 + bfc)[m][d]. Threads 0..511.
__device__ __forceinline__ void fc_delta(const _Float16 (*hb)[HP], const float (*wfc)[H],
                                         const float* __restrict__ bfcs,
                                         const float* __restrict__ xlast,  // [M][D] contiguous
                                         float (*xb)[D], int tid){
  if(tid >= 512) return;
  const int m = tid >> 4, d = (tid >> 3) & 1, ch = tid & 7;
  const _Float16* hp = &hb[m][ch*16];
  float s = 0.f;
#pragma unroll
  for(int j=0;j<16;j++) s = fmaf((float)hp[j], wfc[d][ch*16+j], s);
  s += __shfl_xor(s, 1, 64); s += __shfl_xor(s, 2, 64); s += __shfl_xor(s, 4, 64);
  if(ch == 0){
    xb[m][d] = xlast[m*D + d] - (s + bfcs[d]);
  }
}

__global__ __launch_bounds__(NTH) void traj_kernel(
    const float* __restrict__ pos, const float* __restrict__ speed,
    const float* __restrict__ Wih_pe, const float* __restrict__ Whh_pe,
    const float* __restrict__ bih_pe, const float* __restrict__ bhh_pe,
    const float* __restrict__ Wih_se, const float* __restrict__ Whh_se,
    const float* __restrict__ bih_se, const float* __restrict__ bhh_se,
    const float* __restrict__ ln_g, const float* __restrict__ ln_b,
    const float* __restrict__ Wih_sd, const float* __restrict__ Whh_sd,
    const float* __restrict__ bih_sd, const float* __restrict__ bhh_sd,
    const float* __restrict__ Wih_pd, const float* __restrict__ Whh_pd,
    const float* __restrict__ bih_pd, const float* __restrict__ bhh_pd,
    const float* __restrict__ Wfc, const float* __restrict__ bfc,
    float* __restrict__ out)
{
  __shared__ __align__(16) _Float16 hsh[2][M][HP];    // [buf][m][u]  ~17.4 KB
  __shared__ float tmpf[M][FP];                        // ~16.9 KB each
  __shared__ float hpoN[M][FP];
  __shared__ float cpoN[M][FP];
  __shared__ float seqx[2][T_OBS][M][D];               // ~10.2 KB
  __shared__ float xbuf[M][D];
  __shared__ float wfcs[D][H];
  __shared__ float bfcs[2];
  // total ~79.6 KB; 16 waves/block, 1 block/CU, 4 waves/SIMD

  const int tid  = threadIdx.x;
  const int lane = tid & 63;
  const int wv   = tid >> 6;       // 0..15
  const int wvu  = wv & 7;         // unit group (shared by both row-half wave sets)
  const int mh   = wv >> 3;        // row half: waves 0-7 -> rows 0..15, 8-15 -> 16..31
  const int q    = lane >> 4;
  const int l15  = lane & 15;
  const int row0 = blockIdx.x * M;
  const int u    = 16*wvu + l15;
  const int mrow0= mh*16;
  const int arow = mrow0 + l15;

  // ---- stage inputs ----
  for(int idx = tid; idx < 2*T_OBS*M*D; idx += NTH){
    const int chain = idx / (T_OBS*M*D);
    const int rem   = idx % (T_OBS*M*D);
    const int t = rem / (M*D), e = rem % (M*D);
    const float* src = chain ? speed : pos;
    seqx[chain][t][e>>1][e&1] = src[(size_t)t*BATCH*D + row0*D + e];
  }
  if(tid < D*H) wfcs[tid>>7][tid&127] = Wfc[tid];
  if(tid < 2)   bfcs[tid] = bfc[tid];
  { int* hz = (int*)&hsh[0][0][0];                    // zero buf0 (M*HP fp16 = 2176 ints)
    for(int idx = tid; idx < M*HP/2; idx += NTH) hz[idx] = 0; }

  PhaseConsts P;
  float c[4];
  load_phase(P, Whh_pe, Wih_pe, bih_pe, bhh_pe, wvu, l15, q);
#pragma unroll
  for(int r=0;r<4;r++) c[r] = 0.f;
  __syncthreads();

  // ---------- phase 1: pos encoder ----------
  int cur = 0;
  for(int t=0; t<T_OBS; t++){ cell_step<true>(hsh, cur, &seqx[0][t][0][0], P, c, mrow0, arow, u, l15, q); cur ^= 1; }
  for(int idx=tid; idx<M*H; idx+=NTH){
    const int m = idx>>7, uu = idx&127;
    tmpf[m][uu] = (float)hsh[cur][m][uu];
  }
  __syncthreads();
  layernorm32(tmpf, hpoN, ln_g, ln_b, tid);
  __syncthreads();
#pragma unroll
  for(int r=0;r<4;r++) tmpf[mrow0 + 4*q+r][u] = c[r];
  __syncthreads();
  layernorm32(tmpf, cpoN, ln_g, ln_b, tid);
  __syncthreads();

  // ---------- phase 2: speed encoder ----------
  load_phase(P, Whh_se, Wih_se, bih_se, bhh_se, wvu, l15, q);
#pragma unroll
  for(int r=0;r<4;r++) c[r] = 0.f;
  for(int idx=tid; idx<M*H; idx+=NTH){
    const int m = idx>>7, uu = idx&127;
    hsh[0][m][uu] = (_Float16)0.f;
  }
  cur = 0;
  __syncthreads();
  for(int t=0; t<T_OBS; t++){ cell_step<true>(hsh, cur, &seqx[1][t][0][0], P, c, mrow0, arow, u, l15, q); cur ^= 1; }
  for(int idx=tid; idx<M*H; idx+=NTH){
    const int m = idx>>7, uu = idx&127;
    tmpf[m][uu] = (float)hsh[cur][m][uu];
  }
  __syncthreads();
  layernorm32(tmpf, tmpf, ln_g, ln_b, tid);
  __syncthreads();
  // hds = LN(hsp) + LN(hpo) -> hsh[0]
  for(int idx=tid; idx<M*H; idx+=NTH){
    const int m = idx>>7, uu = idx&127;
    hsh[0][m][uu] = (_Float16)(tmpf[m][uu] + hpoN[m][uu]);
  }
  __syncthreads();
  // cds = LN(csp) + LN(cpo)
#pragma unroll
  for(int r=0;r<4;r++) tmpf[mrow0 + 4*q+r][u] = c[r];
  __syncthreads();
  layernorm32(tmpf, tmpf, ln_g, ln_b, tid);
  __syncthreads();
#pragma unroll
  for(int r=0;r<4;r++) c[r] = tmpf[mrow0 + 4*q+r][u] + cpoN[mrow0 + 4*q+r][u];

  // ---------- phase 3: speed decoder (FC folded into recurrence) ----------
  load_phase_dec(P, Whh_sd, Wih_sd, bih_sd, bhh_sd, Wfc, bfc, wvu, l15, q);
  // dx = x0 - (Wfc@h0 + bfc); h0 = hds already in hsh[0] (visible: barrier above)
  fc_delta(hsh[0], wfcs, bfcs, &seqx[1][T_OBS-1][0][0], xbuf, tid);
  __syncthreads();

  float* spd_out = out + (size_t)PRED*BATCH*D;
  cur = 0;
  cell_step<true>(hsh, cur, &xbuf[0][0], P, c, mrow0, arow, u, l15, q);
  fc_out(hsh[cur^1], wfcs, bfcs, spd_out, row0, tid);
  cur ^= 1;
  for(int t=1; t<PRED; t++){
    cell_step<false>(hsh, cur, nullptr, P, c, mrow0, arow, u, l15, q);
    fc_out(hsh[cur^1], wfcs, bfcs, spd_out + (size_t)t*BATCH*D, row0, tid);
    cur ^= 1;
  }
  __syncthreads();   // protect hsh buffer still being read by last fc_out before reuse

  // ---------- phase 4: pos decoder ----------
  for(int idx=tid; idx<M*H; idx+=NTH){
    const int m = idx>>7, uu = idx&127;
    hsh[0][m][uu] = (_Float16)hpoN[m][uu];
  }
#pragma unroll
  for(int r=0;r<4;r++) c[r] = cpoN[mrow0 + 4*q+r][u];
  load_phase_dec(P, Whh_pd, Wih_pd, bih_pd, bhh_pd, Wfc, bfc, wvu, l15, q);
  __syncthreads();   // hsh[0] (h0 = LN(hpo)) visible
  fc_delta(hsh[0], wfcs, bfcs, &seqx[0][T_OBS-1][0][0], xbuf, tid);
  __syncthreads();   // xbuf visible

  cur = 0;
  cell_step<true>(hsh, cur, &xbuf[0][0], P, c, mrow0, arow, u, l15, q);
  fc_out(hsh[cur^1], wfcs, bfcs, out, row0, tid);
  cur ^= 1;
  for(int t=1; t<PRED; t++){
    cell_step<false>(hsh, cur, nullptr, P, c, mrow0, arow, u, l15, q);
    fc_out(hsh[cur^1], wfcs, bfcs, out + (size_t)t*BATCH*D, row0, tid);
    cur ^= 1;
  }
}

extern "C" void kernel_launch(void* const* d_in, const int* in_sizes, int n_in,
                              void* d_out, int out_size, void* d_ws, size_t ws_size,
                              hipStream_t stream)
{
  const float* pos    = (const float*)d_in[0];
  const float* speed  = (const float*)d_in[1];
  const float* Wih_pe = (const float*)d_in[2];
  const float* Whh_pe = (const float*)d_in[3];
  const float* bih_pe = (const float*)d_in[4];
  const float* bhh_pe = (const float*)d_in[5];
  const float* Wih_se = (const float*)d_in[6];
  const float* Whh_se = (const float*)d_in[7];
  const float* bih_se = (const float*)d_in[8];
  const float* bhh_se = (const float*)d_in[9];
  const float* ln_g   = (const float*)d_in[10];
  const float* ln_b   = (const float*)d_in[11];
  const float* Wih_sd = (const float*)d_in[12];
  const float* Whh_sd = (const float*)d_in[13];
  const float* bih_sd = (const float*)d_in[14];
  const float* bhh_sd = (const float*)d_in[15];
  const float* Wih_pd = (const float*)d_in[16];
  const float* Whh_pd = (const float*)d_in[17];
  const float* bih_pd = (const float*)d_in[18];
  const float* bhh_pd = (const float*)d_in[19];
  const float* Wfc    = (const float*)d_in[20];
  const float* bfc    = (const float*)d_in[21];

  traj_kernel<<<BATCH/M, NTH, 0, stream>>>(
      pos, speed, Wih_pe, Whh_pe, bih_pe, bhh_pe,
      Wih_se, Whh_se, bih_se, bhh_se, ln_g, ln_b,
      Wih_sd, Whh_sd, bih_sd, bhh_sd, Wih_pd, Whh_pd, bih_pd, bhh_pd,
      Wfc, bfc, (float*)d_out);
}

// Round 8
// 972.888 us; speedup vs baseline: 1.0276x; 1.0276x over previous
//
#include <hip/hip_runtime.h>

#define H 128
#define D 2
#define T_OBS 20
#define BATCH 16384
#define PRED 30
#define M 32          // batch rows per block (two 16-row halves, one per wave-group)
#define NTH 1024      // 16 waves: wave wv -> mh = wv>>3 (row half), unit group wv&7
#define HP 136        // padded fp16 h-row stride (272 B, 16B-aligned)
#define FP 132        // padded f32 row stride
#define LN_EPS 1e-5f

typedef __attribute__((ext_vector_type(8))) _Float16 half8_t;
typedef __attribute__((ext_vector_type(4))) float float4_t;

__device__ __forceinline__ float fast_rcp(float x){ return __builtin_amdgcn_rcpf(x); }
__device__ __forceinline__ float sig_f(float x){ return fast_rcp(1.f + __expf(-x)); }
__device__ __forceinline__ float tanh_f(float x){ return 1.f - 2.f*fast_rcp(__expf(2.f*x)+1.f); }

// Per-phase per-wave constants: B-fragments for one 16-unit column group, 4 gates.
// bw[g][ks] = 16 x half8 = 64 VGPRs; + acc[4] (16) + consts ~ 110 total.
// __launch_bounds__(1024,4) caps at 128 -> fits WITHOUT spill (round-7 lesson:
// omitting the min-waves arg let the allocator target 64 VGPR and spill bw).
struct PhaseConsts {
  half8_t bw[4][4];
  float bs[4], w0[4], w1[4];
};

__device__ __forceinline__ void load_phase(PhaseConsts& P, const float* __restrict__ Whh,
                                           const float* __restrict__ Wih,
                                           const float* __restrict__ bih,
                                           const float* __restrict__ bhh,
                                           int wvu, int l15, int q){
#pragma unroll
  for(int g=0; g<4; g++){
    const int n = g*H + 16*wvu + l15;
    P.bs[g] = bih[n] + bhh[n];
    P.w0[g] = Wih[n*D + 0];
    P.w1[g] = Wih[n*D + 1];
#pragma unroll
    for(int ks=0; ks<4; ks++){
      const float* p = Whh + (size_t)n*H + ks*32 + q*8;  // B[k][n]=Whh[n][k]
      float4 a = *(const float4*)p;
      float4 b = *(const float4*)(p+4);
      half8_t f;
      f[0]=(_Float16)a.x; f[1]=(_Float16)a.y; f[2]=(_Float16)a.z; f[3]=(_Float16)a.w;
      f[4]=(_Float16)b.x; f[5]=(_Float16)b.y; f[6]=(_Float16)b.z; f[7]=(_Float16)b.w;
      P.bw[g][ks] = f;
    }
  }
}

// Decoder variant: fold the FC feedback into the recurrent matrix.
//   Wcomb[n][k] = Whh[n][k] + Wih[n][0]*Wfc[0][k] + Wih[n][1]*Wfc[1][k]
//   b'[n]      = bih[n]+bhh[n] + Wih[n][0]*bfc[0] + Wih[n][1]*bfc[1]
// Then for t>=1: gates = Wcomb @ h + b'  (no x-path, no fc on critical path).
// Step 0 uses the fp32 x-path with dx = x0 - (Wfc@h0 + bfc).
// Fold uses EXPLICIT fmaf: deterministic across builds (kills the
// contraction lottery) and single-rounding.
__device__ __forceinline__ void load_phase_dec(PhaseConsts& P, const float* __restrict__ Whh,
                                               const float* __restrict__ Wih,
                                               const float* __restrict__ bih,
                                               const float* __restrict__ bhh,
                                               const float* __restrict__ Wfc,
                                               const float* __restrict__ bfc,
                                               int wvu, int l15, int q){
#pragma unroll
  for(int g=0; g<4; g++){
    const int n = g*H + 16*wvu + l15;
    const float wi0 = Wih[n*D + 0];
    const float wi1 = Wih[n*D + 1];
    P.bs[g] = fmaf(wi1, bfc[1], fmaf(wi0, bfc[0], bih[n] + bhh[n]));
    P.w0[g] = wi0;
    P.w1[g] = wi1;
#pragma unroll
    for(int ks=0; ks<4; ks++){
      const float* p  = Whh + (size_t)n*H + ks*32 + q*8;   // Whh[n][k..k+7]
      const float* f0 = Wfc + 0*H + ks*32 + q*8;           // Wfc[0][k..k+7]
      const float* f1 = Wfc + 1*H + ks*32 + q*8;           // Wfc[1][k..k+7]
      half8_t f;
#pragma unroll
      for(int j=0;j<8;j++){
        f[j] = (_Float16)fmaf(wi1, f1[j], fmaf(wi0, f0[j], p[j]));
      }
      P.bw[g][ks] = f;
    }
  }
}

// One LSTM cell step. Each wave handles its 16-row half (rows mrow0..mrow0+15)
// for its 16-unit group. h read from hsh[cur], x from xsrc[32][2] (when HASX),
// new h written to hsh[cur^1]. c per-lane fp32 (4 rows). One barrier.
template<bool HASX>
__device__ __forceinline__ void cell_step(_Float16 (*hsh)[M][HP], int cur,
                                          const float* __restrict__ xsrc,
                                          const PhaseConsts& P, float (&c)[4],
                                          int mrow0, int arow, int u, int l15, int q){
  float4_t acc[4];
  if constexpr (HASX){
    float x0[4], x1[4];
#pragma unroll
    for(int r=0; r<4; r++){
      x0[r] = xsrc[(mrow0 + 4*q+r)*2 + 0];
      x1[r] = xsrc[(mrow0 + 4*q+r)*2 + 1];
    }
#pragma unroll
    for(int g=0; g<4; g++)
#pragma unroll
      for(int r=0; r<4; r++)
        acc[g][r] = fmaf(P.w1[g], x1[r], fmaf(P.w0[g], x0[r], P.bs[g]));
  } else {
#pragma unroll
    for(int g=0; g<4; g++)
#pragma unroll
      for(int r=0; r<4; r++)
        acc[g][r] = P.bs[g];
  }

#pragma unroll
  for(int ks=0; ks<4; ks++){
    const half8_t a = *(const half8_t*)&hsh[cur][arow][ks*32 + q*8];
#pragma unroll
    for(int g=0; g<4; g++){
      acc[g] = __builtin_amdgcn_mfma_f32_16x16x32_f16(a, P.bw[g][ks], acc[g], 0,0,0);
    }
  }
  const int nxt = cur ^ 1;
#pragma unroll
  for(int r=0; r<4; r++){
    const float iv = sig_f(acc[0][r]);
    const float fv = sig_f(acc[1][r]);
    const float gv = tanh_f(acc[2][r]);
    const float ov = sig_f(acc[3][r]);
    const float cc = fmaf(fv, c[r], iv*gv);
    c[r] = cc;
    const float hv = ov * tanh_f(cc);
    hsh[nxt][mrow0 + 4*q + r][u] = (_Float16)hv;
  }
  __syncthreads();
}

// LayerNorm over 128 units for 32 rows; threads 0..511, 16 threads/row.
__device__ __forceinline__ void layernorm32(const float (*src)[FP], float (*dst)[FP],
                                            const float* __restrict__ g,
                                            const float* __restrict__ b, int tid){
  if(tid >= 512) return;
  const int m = tid >> 4, sub = tid & 15;
  float v[8];
  float s = 0.f, s2 = 0.f;
#pragma unroll
  for(int j=0;j<8;j++){ v[j] = src[m][sub*8+j]; s += v[j]; s2 = fmaf(v[j], v[j], s2); }
#pragma unroll
  for(int msk=1; msk<16; msk<<=1){ s += __shfl_xor(s, msk, 64); s2 += __shfl_xor(s2, msk, 64); }
  const float mean = s * (1.f/H);
  const float var  = s2 * (1.f/H) - mean*mean;
  const float inv  = rsqrtf(var + LN_EPS);
#pragma unroll
  for(int j=0;j<8;j++){
    const int u = sub*8+j;
    dst[m][u] = fmaf((v[j]-mean)*inv, g[u], b[u]);
  }
}

// Output-only FC: cs = h @ Wfc^T + bfc from the fp16 plane; writes global out ONLY.
// No barrier needed: reads of hb stay race-free until the buffer is rewritten two
// cell-steps later (each cell step ends in a barrier). Threads 0..511 (32 rows).
__device__ __forceinline__ void fc_out(const _Float16 (*hb)[HP], const float (*wfc)[H],
                                       const float* __restrict__ bfcs,
                                       float* __restrict__ gout, int row0, int tid){
  if(tid >= 512) return;
  const int m = tid >> 4, d = (tid >> 3) & 1, ch = tid & 7;
  const _Float16* hp = &hb[m][ch*16];
  float s = 0.f;
#pragma unroll
  for(int j=0;j<16;j++) s = fmaf((float)hp[j], wfc[d][ch*16+j], s);
  s += __shfl_xor(s, 1, 64); s += __shfl_xor(s, 2, 64); s += __shfl_xor(s, 4, 64);
  if(ch == 0){
    gout[(size_t)(row0+m)*D + d] = s + bfcs[d];
  }
}

// Step-0 delta: xb[m][d] = xlast[m][d] - (Wfc@h0 + bfc)[m][d]. Threads 0..511.
__device__ __forceinline__ void fc_delta(const _Float16 (*hb)[HP], const float (*wfc)[H],
                                         const float* __restrict__ bfcs,
                                         const float* __restrict__ xlast,  // [M][D] contiguous
                                         float (*xb)[D], int tid){
  if(tid >= 512) return;
  const int m = tid >> 4, d = (tid >> 3) & 1, ch = tid & 7;
  const _Float16* hp = &hb[m][ch*16];
  float s = 0.f;
#pragma unroll
  for(int j=0;j<16;j++) s = fmaf((float)hp[j], wfc[d][ch*16+j], s);
  s += __shfl_xor(s, 1, 64); s += __shfl_xor(s, 2, 64); s += __shfl_xor(s, 4, 64);
  if(ch == 0){
    xb[m][d] = xlast[m*D + d] - (s + bfcs[d]);
  }
}

__global__ __launch_bounds__(NTH, 4) void traj_kernel(
    const float* __restrict__ pos, const float* __restrict__ speed,
    const float* __restrict__ Wih_pe, const float* __restrict__ Whh_pe,
    const float* __restrict__ bih_pe, const float* __restrict__ bhh_pe,
    const float* __restrict__ Wih_se, const float* __restrict__ Whh_se,
    const float* __restrict__ bih_se, const float* __restrict__ bhh_se,
    const float* __restrict__ ln_g, const float* __restrict__ ln_b,
    const float* __restrict__ Wih_sd, const float* __restrict__ Whh_sd,
    const float* __restrict__ bih_sd, const float* __restrict__ bhh_sd,
    const float* __restrict__ Wih_pd, const float* __restrict__ Whh_pd,
    const float* __restrict__ bih_pd, const float* __restrict__ bhh_pd,
    const float* __restrict__ Wfc, const float* __restrict__ bfc,
    float* __restrict__ out)
{
  __shared__ __align__(16) _Float16 hsh[2][M][HP];    // [buf][m][u]  ~17.4 KB
  __shared__ float tmpf[M][FP];                        // ~16.9 KB each
  __shared__ float hpoN[M][FP];
  __shared__ float cpoN[M][FP];
  __shared__ float seqx[2][T_OBS][M][D];               // ~10.2 KB
  __shared__ float xbuf[M][D];
  __shared__ float wfcs[D][H];
  __shared__ float bfcs[2];
  // total ~79.6 KB; 16 waves/block, 1 block/CU, 4 waves/SIMD

  const int tid  = threadIdx.x;
  const int lane = tid & 63;
  const int wv   = tid >> 6;       // 0..15
  const int wvu  = wv & 7;         // unit group (shared by both row-half wave sets)
  const int mh   = wv >> 3;        // row half: waves 0-7 -> rows 0..15, 8-15 -> 16..31
  const int q    = lane >> 4;
  const int l15  = lane & 15;
  const int row0 = blockIdx.x * M;
  const int u    = 16*wvu + l15;
  const int mrow0= mh*16;
  const int arow = mrow0 + l15;

  // ---- stage inputs ----
  for(int idx = tid; idx < 2*T_OBS*M*D; idx += NTH){
    const int chain = idx / (T_OBS*M*D);
    const int rem   = idx % (T_OBS*M*D);
    const int t = rem / (M*D), e = rem % (M*D);
    const float* src = chain ? speed : pos;
    seqx[chain][t][e>>1][e&1] = src[(size_t)t*BATCH*D + row0*D + e];
  }
  if(tid < D*H) wfcs[tid>>7][tid&127] = Wfc[tid];
  if(tid < 2)   bfcs[tid] = bfc[tid];
  { int* hz = (int*)&hsh[0][0][0];                    // zero buf0 (M*HP fp16 = 2176 ints)
    for(int idx = tid; idx < M*HP/2; idx += NTH) hz[idx] = 0; }

  PhaseConsts P;
  float c[4];
  load_phase(P, Whh_pe, Wih_pe, bih_pe, bhh_pe, wvu, l15, q);
#pragma unroll
  for(int r=0;r<4;r++) c[r] = 0.f;
  __syncthreads();

  // ---------- phase 1: pos encoder ----------
  int cur = 0;
  for(int t=0; t<T_OBS; t++){ cell_step<true>(hsh, cur, &seqx[0][t][0][0], P, c, mrow0, arow, u, l15, q); cur ^= 1; }
  for(int idx=tid; idx<M*H; idx+=NTH){
    const int m = idx>>7, uu = idx&127;
    tmpf[m][uu] = (float)hsh[cur][m][uu];
  }
  __syncthreads();
  layernorm32(tmpf, hpoN, ln_g, ln_b, tid);
  __syncthreads();
#pragma unroll
  for(int r=0;r<4;r++) tmpf[mrow0 + 4*q+r][u] = c[r];
  __syncthreads();
  layernorm32(tmpf, cpoN, ln_g, ln_b, tid);
  __syncthreads();

  // ---------- phase 2: speed encoder ----------
  load_phase(P, Whh_se, Wih_se, bih_se, bhh_se, wvu, l15, q);
#pragma unroll
  for(int r=0;r<4;r++) c[r] = 0.f;
  for(int idx=tid; idx<M*H; idx+=NTH){
    const int m = idx>>7, uu = idx&127;
    hsh[0][m][uu] = (_Float16)0.f;
  }
  cur = 0;
  __syncthreads();
  for(int t=0; t<T_OBS; t++){ cell_step<true>(hsh, cur, &seqx[1][t][0][0], P, c, mrow0, arow, u, l15, q); cur ^= 1; }
  for(int idx=tid; idx<M*H; idx+=NTH){
    const int m = idx>>7, uu = idx&127;
    tmpf[m][uu] = (float)hsh[cur][m][uu];
  }
  __syncthreads();
  layernorm32(tmpf, tmpf, ln_g, ln_b, tid);
  __syncthreads();
  // hds = LN(hsp) + LN(hpo) -> hsh[0]
  for(int idx=tid; idx<M*H; idx+=NTH){
    const int m = idx>>7, uu = idx&127;
    hsh[0][m][uu] = (_Float16)(tmpf[m][uu] + hpoN[m][uu]);
  }
  __syncthreads();
  // cds = LN(csp) + LN(cpo)
#pragma unroll
  for(int r=0;r<4;r++) tmpf[mrow0 + 4*q+r][u] = c[r];
  __syncthreads();
  layernorm32(tmpf, tmpf, ln_g, ln_b, tid);
  __syncthreads();
#pragma unroll
  for(int r=0;r<4;r++) c[r] = tmpf[mrow0 + 4*q+r][u] + cpoN[mrow0 + 4*q+r][u];

  // ---------- phase 3: speed decoder (FC folded into recurrence) ----------
  load_phase_dec(P, Whh_sd, Wih_sd, bih_sd, bhh_sd, Wfc, bfc, wvu, l15, q);
  // dx = x0 - (Wfc@h0 + bfc); h0 = hds already in hsh[0] (visible: barrier above)
  fc_delta(hsh[0], wfcs, bfcs, &seqx[1][T_OBS-1][0][0], xbuf, tid);
  __syncthreads();

  float* spd_out = out + (size_t)PRED*BATCH*D;
  cur = 0;
  cell_step<true>(hsh, cur, &xbuf[0][0], P, c, mrow0, arow, u, l15, q);
  fc_out(hsh[cur^1], wfcs, bfcs, spd_out, row0, tid);
  cur ^= 1;
  for(int t=1; t<PRED; t++){
    cell_step<false>(hsh, cur, nullptr, P, c, mrow0, arow, u, l15, q);
    fc_out(hsh[cur^1], wfcs, bfcs, spd_out + (size_t)t*BATCH*D, row0, tid);
    cur ^= 1;
  }
  __syncthreads();   // protect hsh buffer still being read by last fc_out before reuse

  // ---------- phase 4: pos decoder ----------
  for(int idx=tid; idx<M*H; idx+=NTH){
    const int m = idx>>7, uu = idx&127;
    hsh[0][m][uu] = (_Float16)hpoN[m][uu];
  }
#pragma unroll
  for(int r=0;r<4;r++) c[r] = cpoN[mrow0 + 4*q+r][u];
  load_phase_dec(P, Whh_pd, Wih_pd, bih_pd, bhh_pd, Wfc, bfc, wvu, l15, q);
  __syncthreads();   // hsh[0] (h0 = LN(hpo)) visible
  fc_delta(hsh[0], wfcs, bfcs, &seqx[0][T_OBS-1][0][0], xbuf, tid);
  __syncthreads();   // xbuf visible

  cur = 0;
  cell_step<true>(hsh, cur, &xbuf[0][0], P, c, mrow0, arow, u, l15, q);
  fc_out(hsh[cur^1], wfcs, bfcs, out, row0, tid);
  cur ^= 1;
  for(int t=1; t<PRED; t++){
    cell_step<false>(hsh, cur, nullptr, P, c, mrow0, arow, u, l15, q);
    fc_out(hsh[cur^1], wfcs, bfcs, out + (size_t)t*BATCH*D, row0, tid);
    cur ^= 1;
  }
}

extern "C" void kernel_launch(void* const* d_in, const int* in_sizes, int n_in,
                              void* d_out, int out_size, void* d_ws, size_t ws_size,
                              hipStream_t stream)
{
  const float* pos    = (const float*)d_in[0];
  const float* speed  = (const float*)d_in[1];
  const float* Wih_pe = (const float*)d_in[2];
  const float* Whh_pe = (const float*)d_in[3];
  const float* bih_pe = (const float*)d_in[4];
  const float* bhh_pe = (const float*)d_in[5];
  const float* Wih_se = (const float*)d_in[6];
  const float* Whh_se = (const float*)d_in[7];
  const float* bih_se = (const float*)d_in[8];
  const float* bhh_se = (const float*)d_in[9];
  const float* ln_g   = (const float*)d_in[10];
  const float* ln_b   = (const float*)d_in[11];
  const float* Wih_sd = (const float*)d_in[12];
  const float* Whh_sd = (const float*)d_in[13];
  const float* bih_sd = (const float*)d_in[14];
  const float* bhh_sd = (const float*)d_in[15];
  const float* Wih_pd = (const float*)d_in[16];
  const float* Whh_pd = (const float*)d_in[17];
  const float* bih_pd = (const float*)d_in[18];
  const float* bhh_pd = (const float*)d_in[19];
  const float* Wfc    = (const float*)d_in[20];
  const float* bfc    = (const float*)d_in[21];

  traj_kernel<<<BATCH/M, NTH, 0, stream>>>(
      pos, speed, Wih_pe, Whh_pe, bih_pe, bhh_pe,
      Wih_se, Whh_se, bih_se, bhh_se, ln_g, ln_b,
      Wih_sd, Whh_sd, bih_sd, bhh_sd, Wih_pd, Whh_pd, bih_pd, bhh_pd,
      Wfc, bfc, (float*)d_out);
}

// Round 11
// 826.051 us; speedup vs baseline: 1.2103x; 1.1778x over previous
//
#include <hip/hip_runtime.h>

#define H 128
#define D 2
#define T_OBS 20
#define BATCH 16384
#define PRED 30
#define M 32          // batch rows per block (two 16-row halves per wave)
#define NTH 512       // 8 waves; wave wv owns units 16*wv..16*wv+15, all 4 gates, BOTH chains
#define HP 136        // padded fp16 h-row stride
#define FP 132        // padded f32 row stride
#define LN_EPS 1e-5f

typedef __attribute__((ext_vector_type(8))) _Float16 half8_t;
typedef __attribute__((ext_vector_type(4))) float float4_t;

__device__ __forceinline__ float fast_rcp(float x){ return __builtin_amdgcn_rcpf(x); }
__device__ __forceinline__ float sig_f(float x){ return fast_rcp(1.f + __expf(-x)); }
// pinned contraction: always one fma
__device__ __forceinline__ float tanh_f(float x){ return fmaf(-2.f, fast_rcp(__expf(2.f*x)+1.f), 1.f); }

// Per-phase per-wave constants for ONE chain: 64 VGPR bw + 12 consts.
// Two live chains -> ~128 VGPR weights + 64 acc + misc ~ 240 < 256 at (512,2).
struct PhaseConsts {
  half8_t bw[4][4];
  float bs[4], w0[4], w1[4];
};

__device__ __forceinline__ void load_phase(PhaseConsts& P, const float* __restrict__ Whh,
                                           const float* __restrict__ Wih,
                                           const float* __restrict__ bih,
                                           const float* __restrict__ bhh,
                                           int wv, int l15, int q){
#pragma unroll
  for(int g=0; g<4; g++){
    const int n = g*H + 16*wv + l15;
    P.bs[g] = bih[n] + bhh[n];
    P.w0[g] = Wih[n*D + 0];
    P.w1[g] = Wih[n*D + 1];
#pragma unroll
    for(int ks=0; ks<4; ks++){
      const float* p = Whh + (size_t)n*H + ks*32 + q*8;  // B[k][n]=Whh[n][k]
      float4 a = *(const float4*)p;
      float4 b = *(const float4*)(p+4);
      half8_t f;
      f[0]=(_Float16)a.x; f[1]=(_Float16)a.y; f[2]=(_Float16)a.z; f[3]=(_Float16)a.w;
      f[4]=(_Float16)b.x; f[5]=(_Float16)b.y; f[6]=(_Float16)b.z; f[7]=(_Float16)b.w;
      P.bw[g][ks] = f;
    }
  }
}

// Decoder fold: Wcomb = Whh + Wih*Wfc, b' = b + Wih*bfc (explicit fmaf, one rounding).
__device__ __forceinline__ void load_phase_dec(PhaseConsts& P, const float* __restrict__ Whh,
                                               const float* __restrict__ Wih,
                                               const float* __restrict__ bih,
                                               const float* __restrict__ bhh,
                                               const float* __restrict__ Wfc,
                                               const float* __restrict__ bfc,
                                               int wv, int l15, int q){
#pragma unroll
  for(int g=0; g<4; g++){
    const int n = g*H + 16*wv + l15;
    const float wi0 = Wih[n*D + 0];
    const float wi1 = Wih[n*D + 1];
    P.bs[g] = fmaf(wi1, bfc[1], fmaf(wi0, bfc[0], bih[n] + bhh[n]));
    P.w0[g] = wi0;
    P.w1[g] = wi1;
#pragma unroll
    for(int ks=0; ks<4; ks++){
      const float* p  = Whh + (size_t)n*H + ks*32 + q*8;
      const float* f0 = Wfc + 0*H + ks*32 + q*8;
      const float* f1 = Wfc + 1*H + ks*32 + q*8;
      half8_t f;
#pragma unroll
      for(int j=0;j<8;j++){
        f[j] = (_Float16)fmaf(wi1, f1[j], fmaf(wi0, f0[j], p[j]));
      }
      P.bw[g][ks] = f;
    }
  }
}

// Dual-chain LSTM step: chain0 uses Pa (h in hsh[*][0]), chain1 uses Pb (hsh[*][1]).
// Both chains advance in ONE step with ONE barrier. Per chain: 2 mh halves x 4 gates.
template<bool HASX>
__device__ __forceinline__ void cell_dual(_Float16 (*hsh)[2][M][HP], int cur,
                                          const float* __restrict__ xs0,
                                          const float* __restrict__ xs1,
                                          const PhaseConsts& Pa, const PhaseConsts& Pb,
                                          float (&ca)[2][4], float (&cb)[2][4],
                                          int wv, int l15, int q){
  float4_t aa[2][4], ab[2][4];
  if constexpr (HASX){
#pragma unroll
    for(int mh=0; mh<2; mh++){
      float x0[4], x1[4];
#pragma unroll
      for(int r=0; r<4; r++){
        x0[r] = xs0[(mh*16 + 4*q+r)*2 + 0];
        x1[r] = xs0[(mh*16 + 4*q+r)*2 + 1];
      }
#pragma unroll
      for(int g=0; g<4; g++)
#pragma unroll
        for(int r=0; r<4; r++)
          aa[mh][g][r] = fmaf(Pa.w1[g], x1[r], fmaf(Pa.w0[g], x0[r], Pa.bs[g]));
    }
#pragma unroll
    for(int mh=0; mh<2; mh++){
      float x0[4], x1[4];
#pragma unroll
      for(int r=0; r<4; r++){
        x0[r] = xs1[(mh*16 + 4*q+r)*2 + 0];
        x1[r] = xs1[(mh*16 + 4*q+r)*2 + 1];
      }
#pragma unroll
      for(int g=0; g<4; g++)
#pragma unroll
        for(int r=0; r<4; r++)
          ab[mh][g][r] = fmaf(Pb.w1[g], x1[r], fmaf(Pb.w0[g], x0[r], Pb.bs[g]));
    }
  } else {
#pragma unroll
    for(int mh=0; mh<2; mh++)
#pragma unroll
      for(int g=0; g<4; g++)
#pragma unroll
        for(int r=0; r<4; r++){
          aa[mh][g][r] = Pa.bs[g];
          ab[mh][g][r] = Pb.bs[g];
        }
  }

#pragma unroll
  for(int ks=0; ks<4; ks++){
#pragma unroll
    for(int mh=0; mh<2; mh++){
      const half8_t h0 = *(const half8_t*)&hsh[cur][0][mh*16 + l15][ks*32 + q*8];
#pragma unroll
      for(int g=0; g<4; g++)
        aa[mh][g] = __builtin_amdgcn_mfma_f32_16x16x32_f16(h0, Pa.bw[g][ks], aa[mh][g], 0,0,0);
      const half8_t h1 = *(const half8_t*)&hsh[cur][1][mh*16 + l15][ks*32 + q*8];
#pragma unroll
      for(int g=0; g<4; g++)
        ab[mh][g] = __builtin_amdgcn_mfma_f32_16x16x32_f16(h1, Pb.bw[g][ks], ab[mh][g], 0,0,0);
    }
  }
  const int nxt = cur ^ 1;
  const int u = 16*wv + l15;
#pragma unroll
  for(int mh=0; mh<2; mh++){
#pragma unroll
    for(int r=0; r<4; r++){
      const int m = mh*16 + 4*q + r;
      {
        const float iv = sig_f(aa[mh][0][r]);
        const float fv = sig_f(aa[mh][1][r]);
        const float gv = tanh_f(aa[mh][2][r]);
        const float ov = sig_f(aa[mh][3][r]);
        const float cc = fmaf(fv, ca[mh][r], iv*gv);
        ca[mh][r] = cc;
        hsh[nxt][0][m][u] = (_Float16)(ov * tanh_f(cc));
      }
      {
        const float iv = sig_f(ab[mh][0][r]);
        const float fv = sig_f(ab[mh][1][r]);
        const float gv = tanh_f(ab[mh][2][r]);
        const float ov = sig_f(ab[mh][3][r]);
        const float cc = fmaf(fv, cb[mh][r], iv*gv);
        cb[mh][r] = cc;
        hsh[nxt][1][m][u] = (_Float16)(ov * tanh_f(cc));
      }
    }
  }
  __syncthreads();
}

// LayerNorm over 128 units for 32 rows; all 512 threads, 16 threads/row.
__device__ __forceinline__ void layernorm32(const float (*src)[FP], float (*dst)[FP],
                                            const float* __restrict__ g,
                                            const float* __restrict__ b, int tid){
  const int m = tid >> 4, sub = tid & 15;
  float v[8];
  float s = 0.f, s2 = 0.f;
#pragma unroll
  for(int j=0;j<8;j++){ v[j] = src[m][sub*8+j]; s += v[j]; s2 = fmaf(v[j], v[j], s2); }
#pragma unroll
  for(int msk=1; msk<16; msk<<=1){ s += __shfl_xor(s, msk, 64); s2 += __shfl_xor(s2, msk, 64); }
  const float mean = s * (1.f/H);
  const float var  = fmaf(-mean, mean, s2 * (1.f/H));   // pinned contraction
  const float inv  = rsqrtf(var + LN_EPS);
#pragma unroll
  for(int j=0;j<8;j++){
    const int u = sub*8+j;
    dst[m][u] = fmaf((v[j]-mean)*inv, g[u], b[u]);
  }
}

// Dual FC: ALL 512 threads cover m=0..31 (tid>>4); each thread loops over BOTH
// chains (R10 bug: splitting threads by chain halved row coverage -> rows 16..31
// never written). chain0 (speed-dec h) -> g0; chain1 (pos-dec h) -> g1.
// No barrier needed: hb rewritten 2 steps later, with a barrier in between.
__device__ __forceinline__ void fc_out_dual(const _Float16 (*hb)[M][HP], const float (*wfc)[H],
                                            const float* __restrict__ bfcs,
                                            float* __restrict__ g0, float* __restrict__ g1,
                                            int row0, int tid){
  const int m = tid >> 4, d = (tid >> 3) & 1, cn = tid & 7;
#pragma unroll
  for(int ch=0; ch<2; ch++){
    const _Float16* hp = &hb[ch][m][cn*16];
    float s = 0.f;
#pragma unroll
    for(int j=0;j<16;j++) s = fmaf((float)hp[j], wfc[d][cn*16+j], s);
    s += __shfl_xor(s, 1, 64); s += __shfl_xor(s, 2, 64); s += __shfl_xor(s, 4, 64);
    if(cn == 0){
      float* g = ch ? g1 : g0;
      g[(size_t)(row0+m)*D + d] = s + bfcs[d];
    }
  }
}

// Dual step-0 delta: xb[ch][m][d] = xlast_ch[m][d] - (Wfc@h0_ch + bfc)[m][d].
// All 512 threads, loop over chains (same fix as fc_out_dual).
__device__ __forceinline__ void fc_delta_dual(const _Float16 (*hb)[M][HP], const float (*wfc)[H],
                                              const float* __restrict__ bfcs,
                                              const float* __restrict__ xl0,  // [M][D]
                                              const float* __restrict__ xl1,  // [M][D]
                                              float (*xb)[M][D], int tid){
  const int m = tid >> 4, d = (tid >> 3) & 1, cn = tid & 7;
#pragma unroll
  for(int ch=0; ch<2; ch++){
    const _Float16* hp = &hb[ch][m][cn*16];
    float s = 0.f;
#pragma unroll
    for(int j=0;j<16;j++) s = fmaf((float)hp[j], wfc[d][cn*16+j], s);
    s += __shfl_xor(s, 1, 64); s += __shfl_xor(s, 2, 64); s += __shfl_xor(s, 4, 64);
    if(cn == 0){
      const float* xl = ch ? xl1 : xl0;
      xb[ch][m][d] = xl[m*D + d] - (s + bfcs[d]);
    }
  }
}

__global__ __launch_bounds__(NTH, 2) void traj_kernel(
    const float* __restrict__ pos, const float* __restrict__ speed,
    const float* __restrict__ Wih_pe, const float* __restrict__ Whh_pe,
    const float* __restrict__ bih_pe, const float* __restrict__ bhh_pe,
    const float* __restrict__ Wih_se, const float* __restrict__ Whh_se,
    const float* __restrict__ bih_se, const float* __restrict__ bhh_se,
    const float* __restrict__ ln_g, const float* __restrict__ ln_b,
    const float* __restrict__ Wih_sd, const float* __restrict__ Whh_sd,
    const float* __restrict__ bih_sd, const float* __restrict__ bhh_sd,
    const float* __restrict__ Wih_pd, const float* __restrict__ Whh_pd,
    const float* __restrict__ bih_pd, const float* __restrict__ bhh_pd,
    const float* __restrict__ Wfc, const float* __restrict__ bfc,
    float* __restrict__ out)
{
  __shared__ __align__(16) _Float16 hsh[2][2][M][HP]; // [buf][chain][m][u] ~34.8 KB
  __shared__ float tmpf[M][FP];                        // ~16.9 KB each
  __shared__ float hpoN[M][FP];
  __shared__ float cpoN[M][FP];
  __shared__ float seqx[2][T_OBS][M][D];               // ~10.2 KB
  __shared__ float xbuf[2][M][D];
  __shared__ float wfcs[D][H];
  __shared__ float bfcs[2];
  // total ~96 KB; 1 block/CU (register-bound anyway)

  const int tid  = threadIdx.x;
  const int lane = tid & 63;
  const int wv   = tid >> 6;       // 0..7 -> unit group
  const int q    = lane >> 4;
  const int l15  = lane & 15;
  const int row0 = blockIdx.x * M;
  const int u    = 16*wv + l15;

  // ---- stage inputs ----
  for(int idx = tid; idx < 2*T_OBS*M*D; idx += NTH){
    const int chain = idx / (T_OBS*M*D);
    const int rem   = idx % (T_OBS*M*D);
    const int t = rem / (M*D), e = rem % (M*D);
    const float* src = chain ? speed : pos;
    seqx[chain][t][e>>1][e&1] = src[(size_t)t*BATCH*D + row0*D + e];
  }
  if(tid < D*H) wfcs[tid>>7][tid&127] = Wfc[tid];
  if(tid < 2)   bfcs[tid] = bfc[tid];
  { int* hz = (int*)&hsh[0][0][0][0];                 // zero buf0, both chains
    for(int idx = tid; idx < M*HP; idx += NTH) hz[idx] = 0; }

  PhaseConsts Pa, Pb;
  float ca[2][4], cb[2][4];
  // ENC: chain0 = pos encoder, chain1 = speed encoder
  load_phase(Pa, Whh_pe, Wih_pe, bih_pe, bhh_pe, wv, l15, q);
  load_phase(Pb, Whh_se, Wih_se, bih_se, bhh_se, wv, l15, q);
#pragma unroll
  for(int mh=0;mh<2;mh++)
#pragma unroll
    for(int r=0;r<4;r++){ ca[mh][r] = 0.f; cb[mh][r] = 0.f; }
  __syncthreads();

  // ---------- merged encoders: 20 dual steps ----------
  int cur = 0;
  for(int t=0; t<T_OBS; t++){
    cell_dual<true>(hsh, cur, &seqx[0][t][0][0], &seqx[1][t][0][0], Pa, Pb, ca, cb, wv, l15, q);
    cur ^= 1;
  }
  // pos h -> LN -> hpoN
  for(int idx=tid; idx<M*H; idx+=NTH){
    const int m = idx>>7, uu = idx&127;
    tmpf[m][uu] = (float)hsh[cur][0][m][uu];
  }
  __syncthreads();
  layernorm32(tmpf, hpoN, ln_g, ln_b, tid);
  __syncthreads();
  // speed h -> LN -> tmpf (hspN)
  for(int idx=tid; idx<M*H; idx+=NTH){
    const int m = idx>>7, uu = idx&127;
    tmpf[m][uu] = (float)hsh[cur][1][m][uu];
  }
  __syncthreads();
  layernorm32(tmpf, tmpf, ln_g, ln_b, tid);
  __syncthreads();
  // decoder h0s: chain0 (speed-dec) h = hds = LN(hsp)+LN(hpo); chain1 (pos-dec) h = LN(hpo)
  for(int idx=tid; idx<M*H; idx+=NTH){
    const int m = idx>>7, uu = idx&127;
    hsh[0][0][m][uu] = (_Float16)(tmpf[m][uu] + hpoN[m][uu]);
    hsh[0][1][m][uu] = (_Float16)hpoN[m][uu];
  }
  __syncthreads();
  // c_pos -> LN -> cpoN
#pragma unroll
  for(int mh=0;mh<2;mh++)
#pragma unroll
    for(int r=0;r<4;r++) tmpf[mh*16 + 4*q+r][u] = ca[mh][r];
  __syncthreads();
  layernorm32(tmpf, cpoN, ln_g, ln_b, tid);
  __syncthreads();
  // c_speed -> LN -> tmpf
#pragma unroll
  for(int mh=0;mh<2;mh++)
#pragma unroll
    for(int r=0;r<4;r++) tmpf[mh*16 + 4*q+r][u] = cb[mh][r];
  __syncthreads();
  layernorm32(tmpf, tmpf, ln_g, ln_b, tid);
  __syncthreads();
  // decoder c0s: chain0 cds = LN(csp)+LN(cpo); chain1 = LN(cpo)
#pragma unroll
  for(int mh=0;mh<2;mh++)
#pragma unroll
    for(int r=0;r<4;r++){
      const int m = mh*16 + 4*q + r;
      ca[mh][r] = tmpf[m][u] + cpoN[m][u];
      cb[mh][r] = cpoN[m][u];
    }

  // DEC: chain0 = speed decoder, chain1 = pos decoder (FC folded into recurrence)
  load_phase_dec(Pa, Whh_sd, Wih_sd, bih_sd, bhh_sd, Wfc, bfc, wv, l15, q);
  load_phase_dec(Pb, Whh_pd, Wih_pd, bih_pd, bhh_pd, Wfc, bfc, wv, l15, q);
  // dx per chain (h0s in hsh[0], visible: barriers above)
  fc_delta_dual(hsh[0], wfcs, bfcs, &seqx[1][T_OBS-1][0][0], &seqx[0][T_OBS-1][0][0], xbuf, tid);
  __syncthreads();

  // ---------- merged decoders: 30 dual steps ----------
  float* spd_out = out + (size_t)PRED*BATCH*D;
  cur = 0;
  cell_dual<true>(hsh, cur, &xbuf[0][0][0], &xbuf[1][0][0], Pa, Pb, ca, cb, wv, l15, q);
  fc_out_dual(hsh[cur^1], wfcs, bfcs, spd_out, out, row0, tid);
  cur ^= 1;
  for(int t=1; t<PRED; t++){
    cell_dual<false>(hsh, cur, nullptr, nullptr, Pa, Pb, ca, cb, wv, l15, q);
    fc_out_dual(hsh[cur^1], wfcs, bfcs,
                spd_out + (size_t)t*BATCH*D, out + (size_t)t*BATCH*D, row0, tid);
    cur ^= 1;
  }
}

extern "C" void kernel_launch(void* const* d_in, const int* in_sizes, int n_in,
                              void* d_out, int out_size, void* d_ws, size_t ws_size,
                              hipStream_t stream)
{
  const float* pos    = (const float*)d_in[0];
  const float* speed  = (const float*)d_in[1];
  const float* Wih_pe = (const float*)d_in[2];
  const float* Whh_pe = (const float*)d_in[3];
  const float* bih_pe = (const float*)d_in[4];
  const float* bhh_pe = (const float*)d_in[5];
  const float* Wih_se = (const float*)d_in[6];
  const float* Whh_se = (const float*)d_in[7];
  const float* bih_se = (const float*)d_in[8];
  const float* bhh_se = (const float*)d_in[9];
  const float* ln_g   = (const float*)d_in[10];
  const float* ln_b   = (const float*)d_in[11];
  const float* Wih_sd = (const float*)d_in[12];
  const float* Whh_sd = (const float*)d_in[13];
  const float* bih_sd = (const float*)d_in[14];
  const float* bhh_sd = (const float*)d_in[15];
  const float* Wih_pd = (const float*)d_in[16];
  const float* Whh_pd = (const float*)d_in[17];
  const float* bih_pd = (const float*)d_in[18];
  const float* bhh_pd = (const float*)d_in[19];
  const float* Wfc    = (const float*)d_in[20];
  const float* bfc    = (const float*)d_in[21];

  traj_kernel<<<BATCH/M, NTH, 0, stream>>>(
      pos, speed, Wih_pe, Whh_pe, bih_pe, bhh_pe,
      Wih_se, Whh_se, bih_se, bhh_se, ln_g, ln_b,
      Wih_sd, Whh_sd, bih_sd, bhh_sd, Wih_pd, Whh_pd, bih_pd, bhh_pd,
      Wfc, bfc, (float*)d_out);
}

// Round 12
// 822.220 us; speedup vs baseline: 1.2159x; 1.0047x over previous
//
#include <hip/hip_runtime.h>

#define H 128
#define D 2
#define T_OBS 20
#define BATCH 16384
#define PRED 30
#define M 32          // batch rows per block (two 16-row halves per wave)
#define NTH 512       // 8 waves; wave wv owns units 16*wv..16*wv+15, all 4 gates, BOTH chains
#define HP 136        // padded fp16 h-row stride
#define FP 132        // padded f32 row stride
#define LN_EPS 1e-5f

typedef __attribute__((ext_vector_type(8))) _Float16 half8_t;
typedef __attribute__((ext_vector_type(4))) float float4_t;

__device__ __forceinline__ float fast_rcp(float x){ return __builtin_amdgcn_rcpf(x); }
__device__ __forceinline__ float sig_f(float x){ return fast_rcp(1.f + __expf(-x)); }
// pinned contraction: always one fma
__device__ __forceinline__ float tanh_f(float x){ return fmaf(-2.f, fast_rcp(__expf(2.f*x)+1.f), 1.f); }

// Per-phase per-wave constants for ONE chain: 64 VGPR bw + 12 consts.
// Two live chains -> ~128 VGPR weights + 64 acc + misc ~ 240.
// __launch_bounds__(512,1) -> 512-reg budget so the allocator can grant ~240
// without spilling (R11 lesson: at (512,2) it stops at 128 arch VGPRs and
// spills 950 MB/dispatch of bw reloads).
struct PhaseConsts {
  half8_t bw[4][4];
  float bs[4], w0[4], w1[4];
};

__device__ __forceinline__ void load_phase(PhaseConsts& P, const float* __restrict__ Whh,
                                           const float* __restrict__ Wih,
                                           const float* __restrict__ bih,
                                           const float* __restrict__ bhh,
                                           int wv, int l15, int q){
#pragma unroll
  for(int g=0; g<4; g++){
    const int n = g*H + 16*wv + l15;
    P.bs[g] = bih[n] + bhh[n];
    P.w0[g] = Wih[n*D + 0];
    P.w1[g] = Wih[n*D + 1];
#pragma unroll
    for(int ks=0; ks<4; ks++){
      const float* p = Whh + (size_t)n*H + ks*32 + q*8;  // B[k][n]=Whh[n][k]
      float4 a = *(const float4*)p;
      float4 b = *(const float4*)(p+4);
      half8_t f;
      f[0]=(_Float16)a.x; f[1]=(_Float16)a.y; f[2]=(_Float16)a.z; f[3]=(_Float16)a.w;
      f[4]=(_Float16)b.x; f[5]=(_Float16)b.y; f[6]=(_Float16)b.z; f[7]=(_Float16)b.w;
      P.bw[g][ks] = f;
    }
  }
}

// Decoder fold: Wcomb = Whh + Wih*Wfc, b' = b + Wih*bfc (explicit fmaf, one rounding).
__device__ __forceinline__ void load_phase_dec(PhaseConsts& P, const float* __restrict__ Whh,
                                               const float* __restrict__ Wih,
                                               const float* __restrict__ bih,
                                               const float* __restrict__ bhh,
                                               const float* __restrict__ Wfc,
                                               const float* __restrict__ bfc,
                                               int wv, int l15, int q){
#pragma unroll
  for(int g=0; g<4; g++){
    const int n = g*H + 16*wv + l15;
    const float wi0 = Wih[n*D + 0];
    const float wi1 = Wih[n*D + 1];
    P.bs[g] = fmaf(wi1, bfc[1], fmaf(wi0, bfc[0], bih[n] + bhh[n]));
    P.w0[g] = wi0;
    P.w1[g] = wi1;
#pragma unroll
    for(int ks=0; ks<4; ks++){
      const float* p  = Whh + (size_t)n*H + ks*32 + q*8;
      const float* f0 = Wfc + 0*H + ks*32 + q*8;
      const float* f1 = Wfc + 1*H + ks*32 + q*8;
      half8_t f;
#pragma unroll
      for(int j=0;j<8;j++){
        f[j] = (_Float16)fmaf(wi1, f1[j], fmaf(wi0, f0[j], p[j]));
      }
      P.bw[g][ks] = f;
    }
  }
}

// Dual-chain LSTM step: chain0 uses Pa (h in hsh[*][0]), chain1 uses Pb (hsh[*][1]).
// Both chains advance in ONE step with ONE barrier. Per chain: 2 mh halves x 4 gates.
template<bool HASX>
__device__ __forceinline__ void cell_dual(_Float16 (*hsh)[2][M][HP], int cur,
                                          const float* __restrict__ xs0,
                                          const float* __restrict__ xs1,
                                          const PhaseConsts& Pa, const PhaseConsts& Pb,
                                          float (&ca)[2][4], float (&cb)[2][4],
                                          int wv, int l15, int q){
  float4_t aa[2][4], ab[2][4];
  if constexpr (HASX){
#pragma unroll
    for(int mh=0; mh<2; mh++){
      float x0[4], x1[4];
#pragma unroll
      for(int r=0; r<4; r++){
        x0[r] = xs0[(mh*16 + 4*q+r)*2 + 0];
        x1[r] = xs0[(mh*16 + 4*q+r)*2 + 1];
      }
#pragma unroll
      for(int g=0; g<4; g++)
#pragma unroll
        for(int r=0; r<4; r++)
          aa[mh][g][r] = fmaf(Pa.w1[g], x1[r], fmaf(Pa.w0[g], x0[r], Pa.bs[g]));
    }
#pragma unroll
    for(int mh=0; mh<2; mh++){
      float x0[4], x1[4];
#pragma unroll
      for(int r=0; r<4; r++){
        x0[r] = xs1[(mh*16 + 4*q+r)*2 + 0];
        x1[r] = xs1[(mh*16 + 4*q+r)*2 + 1];
      }
#pragma unroll
      for(int g=0; g<4; g++)
#pragma unroll
        for(int r=0; r<4; r++)
          ab[mh][g][r] = fmaf(Pb.w1[g], x1[r], fmaf(Pb.w0[g], x0[r], Pb.bs[g]));
    }
  } else {
#pragma unroll
    for(int mh=0; mh<2; mh++)
#pragma unroll
      for(int g=0; g<4; g++)
#pragma unroll
        for(int r=0; r<4; r++){
          aa[mh][g][r] = Pa.bs[g];
          ab[mh][g][r] = Pb.bs[g];
        }
  }

#pragma unroll
  for(int ks=0; ks<4; ks++){
#pragma unroll
    for(int mh=0; mh<2; mh++){
      const half8_t h0 = *(const half8_t*)&hsh[cur][0][mh*16 + l15][ks*32 + q*8];
#pragma unroll
      for(int g=0; g<4; g++)
        aa[mh][g] = __builtin_amdgcn_mfma_f32_16x16x32_f16(h0, Pa.bw[g][ks], aa[mh][g], 0,0,0);
      const half8_t h1 = *(const half8_t*)&hsh[cur][1][mh*16 + l15][ks*32 + q*8];
#pragma unroll
      for(int g=0; g<4; g++)
        ab[mh][g] = __builtin_amdgcn_mfma_f32_16x16x32_f16(h1, Pb.bw[g][ks], ab[mh][g], 0,0,0);
    }
  }
  const int nxt = cur ^ 1;
  const int u = 16*wv + l15;
#pragma unroll
  for(int mh=0; mh<2; mh++){
#pragma unroll
    for(int r=0; r<4; r++){
      const int m = mh*16 + 4*q + r;
      {
        const float iv = sig_f(aa[mh][0][r]);
        const float fv = sig_f(aa[mh][1][r]);
        const float gv = tanh_f(aa[mh][2][r]);
        const float ov = sig_f(aa[mh][3][r]);
        const float cc = fmaf(fv, ca[mh][r], iv*gv);
        ca[mh][r] = cc;
        hsh[nxt][0][m][u] = (_Float16)(ov * tanh_f(cc));
      }
      {
        const float iv = sig_f(ab[mh][0][r]);
        const float fv = sig_f(ab[mh][1][r]);
        const float gv = tanh_f(ab[mh][2][r]);
        const float ov = sig_f(ab[mh][3][r]);
        const float cc = fmaf(fv, cb[mh][r], iv*gv);
        cb[mh][r] = cc;
        hsh[nxt][1][m][u] = (_Float16)(ov * tanh_f(cc));
      }
    }
  }
  __syncthreads();
}

// LayerNorm over 128 units for 32 rows; all 512 threads, 16 threads/row.
__device__ __forceinline__ void layernorm32(const float (*src)[FP], float (*dst)[FP],
                                            const float* __restrict__ g,
                                            const float* __restrict__ b, int tid){
  const int m = tid >> 4, sub = tid & 15;
  float v[8];
  float s = 0.f, s2 = 0.f;
#pragma unroll
  for(int j=0;j<8;j++){ v[j] = src[m][sub*8+j]; s += v[j]; s2 = fmaf(v[j], v[j], s2); }
#pragma unroll
  for(int msk=1; msk<16; msk<<=1){ s += __shfl_xor(s, msk, 64); s2 += __shfl_xor(s2, msk, 64); }
  const float mean = s * (1.f/H);
  const float var  = fmaf(-mean, mean, s2 * (1.f/H));   // pinned contraction
  const float inv  = rsqrtf(var + LN_EPS);
#pragma unroll
  for(int j=0;j<8;j++){
    const int u = sub*8+j;
    dst[m][u] = fmaf((v[j]-mean)*inv, g[u], b[u]);
  }
}

// Dual FC: ALL 512 threads cover m=0..31 (tid>>4); each thread loops over BOTH
// chains. chain0 (speed-dec h) -> g0; chain1 (pos-dec h) -> g1.
// No barrier needed: hb rewritten 2 steps later, with a barrier in between.
__device__ __forceinline__ void fc_out_dual(const _Float16 (*hb)[M][HP], const float (*wfc)[H],
                                            const float* __restrict__ bfcs,
                                            float* __restrict__ g0, float* __restrict__ g1,
                                            int row0, int tid){
  const int m = tid >> 4, d = (tid >> 3) & 1, cn = tid & 7;
#pragma unroll
  for(int ch=0; ch<2; ch++){
    const _Float16* hp = &hb[ch][m][cn*16];
    float s = 0.f;
#pragma unroll
    for(int j=0;j<16;j++) s = fmaf((float)hp[j], wfc[d][cn*16+j], s);
    s += __shfl_xor(s, 1, 64); s += __shfl_xor(s, 2, 64); s += __shfl_xor(s, 4, 64);
    if(cn == 0){
      float* g = ch ? g1 : g0;
      g[(size_t)(row0+m)*D + d] = s + bfcs[d];
    }
  }
}

// Dual step-0 delta: xb[ch][m][d] = xlast_ch[m][d] - (Wfc@h0_ch + bfc)[m][d].
// All 512 threads, loop over chains.
__device__ __forceinline__ void fc_delta_dual(const _Float16 (*hb)[M][HP], const float (*wfc)[H],
                                              const float* __restrict__ bfcs,
                                              const float* __restrict__ xl0,  // [M][D]
                                              const float* __restrict__ xl1,  // [M][D]
                                              float (*xb)[M][D], int tid){
  const int m = tid >> 4, d = (tid >> 3) & 1, cn = tid & 7;
#pragma unroll
  for(int ch=0; ch<2; ch++){
    const _Float16* hp = &hb[ch][m][cn*16];
    float s = 0.f;
#pragma unroll
    for(int j=0;j<16;j++) s = fmaf((float)hp[j], wfc[d][cn*16+j], s);
    s += __shfl_xor(s, 1, 64); s += __shfl_xor(s, 2, 64); s += __shfl_xor(s, 4, 64);
    if(cn == 0){
      const float* xl = ch ? xl1 : xl0;
      xb[ch][m][d] = xl[m*D + d] - (s + bfcs[d]);
    }
  }
}

__global__ __launch_bounds__(NTH, 1) void traj_kernel(
    const float* __restrict__ pos, const float* __restrict__ speed,
    const float* __restrict__ Wih_pe, const float* __restrict__ Whh_pe,
    const float* __restrict__ bih_pe, const float* __restrict__ bhh_pe,
    const float* __restrict__ Wih_se, const float* __restrict__ Whh_se,
    const float* __restrict__ bih_se, const float* __restrict__ bhh_se,
    const float* __restrict__ ln_g, const float* __restrict__ ln_b,
    const float* __restrict__ Wih_sd, const float* __restrict__ Whh_sd,
    const float* __restrict__ bih_sd, const float* __restrict__ bhh_sd,
    const float* __restrict__ Wih_pd, const float* __restrict__ Whh_pd,
    const float* __restrict__ bih_pd, const float* __restrict__ bhh_pd,
    const float* __restrict__ Wfc, const float* __restrict__ bfc,
    float* __restrict__ out)
{
  __shared__ __align__(16) _Float16 hsh[2][2][M][HP]; // [buf][chain][m][u] ~34.8 KB
  __shared__ float tmpf[M][FP];                        // ~16.9 KB each
  __shared__ float hpoN[M][FP];
  __shared__ float cpoN[M][FP];
  __shared__ float seqx[2][T_OBS][M][D];               // ~10.2 KB
  __shared__ float xbuf[2][M][D];
  __shared__ float wfcs[D][H];
  __shared__ float bfcs[2];
  // total ~96 KB; 1 block/CU

  const int tid  = threadIdx.x;
  const int lane = tid & 63;
  const int wv   = tid >> 6;       // 0..7 -> unit group
  const int q    = lane >> 4;
  const int l15  = lane & 15;
  const int row0 = blockIdx.x * M;
  const int u    = 16*wv + l15;

  // ---- stage inputs ----
  for(int idx = tid; idx < 2*T_OBS*M*D; idx += NTH){
    const int chain = idx / (T_OBS*M*D);
    const int rem   = idx % (T_OBS*M*D);
    const int t = rem / (M*D), e = rem % (M*D);
    const float* src = chain ? speed : pos;
    seqx[chain][t][e>>1][e&1] = src[(size_t)t*BATCH*D + row0*D + e];
  }
  if(tid < D*H) wfcs[tid>>7][tid&127] = Wfc[tid];
  if(tid < 2)   bfcs[tid] = bfc[tid];
  { int* hz = (int*)&hsh[0][0][0][0];                 // zero buf0, both chains
    for(int idx = tid; idx < M*HP; idx += NTH) hz[idx] = 0; }

  PhaseConsts Pa, Pb;
  float ca[2][4], cb[2][4];
  // ENC: chain0 = pos encoder, chain1 = speed encoder
  load_phase(Pa, Whh_pe, Wih_pe, bih_pe, bhh_pe, wv, l15, q);
  load_phase(Pb, Whh_se, Wih_se, bih_se, bhh_se, wv, l15, q);
#pragma unroll
  for(int mh=0;mh<2;mh++)
#pragma unroll
    for(int r=0;r<4;r++){ ca[mh][r] = 0.f; cb[mh][r] = 0.f; }
  __syncthreads();

  // ---------- merged encoders: 20 dual steps ----------
  int cur = 0;
  for(int t=0; t<T_OBS; t++){
    cell_dual<true>(hsh, cur, &seqx[0][t][0][0], &seqx[1][t][0][0], Pa, Pb, ca, cb, wv, l15, q);
    cur ^= 1;
  }
  // pos h -> LN -> hpoN
  for(int idx=tid; idx<M*H; idx+=NTH){
    const int m = idx>>7, uu = idx&127;
    tmpf[m][uu] = (float)hsh[cur][0][m][uu];
  }
  __syncthreads();
  layernorm32(tmpf, hpoN, ln_g, ln_b, tid);
  __syncthreads();
  // speed h -> LN -> tmpf (hspN)
  for(int idx=tid; idx<M*H; idx+=NTH){
    const int m = idx>>7, uu = idx&127;
    tmpf[m][uu] = (float)hsh[cur][1][m][uu];
  }
  __syncthreads();
  layernorm32(tmpf, tmpf, ln_g, ln_b, tid);
  __syncthreads();
  // decoder h0s: chain0 (speed-dec) h = hds = LN(hsp)+LN(hpo); chain1 (pos-dec) h = LN(hpo)
  for(int idx=tid; idx<M*H; idx+=NTH){
    const int m = idx>>7, uu = idx&127;
    hsh[0][0][m][uu] = (_Float16)(tmpf[m][uu] + hpoN[m][uu]);
    hsh[0][1][m][uu] = (_Float16)hpoN[m][uu];
  }
  __syncthreads();
  // c_pos -> LN -> cpoN
#pragma unroll
  for(int mh=0;mh<2;mh++)
#pragma unroll
    for(int r=0;r<4;r++) tmpf[mh*16 + 4*q+r][u] = ca[mh][r];
  __syncthreads();
  layernorm32(tmpf, cpoN, ln_g, ln_b, tid);
  __syncthreads();
  // c_speed -> LN -> tmpf
#pragma unroll
  for(int mh=0;mh<2;mh++)
#pragma unroll
    for(int r=0;r<4;r++) tmpf[mh*16 + 4*q+r][u] = cb[mh][r];
  __syncthreads();
  layernorm32(tmpf, tmpf, ln_g, ln_b, tid);
  __syncthreads();
  // decoder c0s: chain0 cds = LN(csp)+LN(cpo); chain1 = LN(cpo)
#pragma unroll
  for(int mh=0;mh<2;mh++)
#pragma unroll
    for(int r=0;r<4;r++){
      const int m = mh*16 + 4*q + r;
      ca[mh][r] = tmpf[m][u] + cpoN[m][u];
      cb[mh][r] = cpoN[m][u];
    }

  // DEC: chain0 = speed decoder, chain1 = pos decoder (FC folded into recurrence)
  load_phase_dec(Pa, Whh_sd, Wih_sd, bih_sd, bhh_sd, Wfc, bfc, wv, l15, q);
  load_phase_dec(Pb, Whh_pd, Wih_pd, bih_pd, bhh_pd, Wfc, bfc, wv, l15, q);
  // dx per chain (h0s in hsh[0], visible: barriers above)
  fc_delta_dual(hsh[0], wfcs, bfcs, &seqx[1][T_OBS-1][0][0], &seqx[0][T_OBS-1][0][0], xbuf, tid);
  __syncthreads();

  // ---------- merged decoders: 30 dual steps ----------
  float* spd_out = out + (size_t)PRED*BATCH*D;
  cur = 0;
  cell_dual<true>(hsh, cur, &xbuf[0][0][0], &xbuf[1][0][0], Pa, Pb, ca, cb, wv, l15, q);
  fc_out_dual(hsh[cur^1], wfcs, bfcs, spd_out, out, row0, tid);
  cur ^= 1;
  for(int t=1; t<PRED; t++){
    cell_dual<false>(hsh, cur, nullptr, nullptr, Pa, Pb, ca, cb, wv, l15, q);
    fc_out_dual(hsh[cur^1], wfcs, bfcs,
                spd_out + (size_t)t*BATCH*D, out + (size_t)t*BATCH*D, row0, tid);
    cur ^= 1;
  }
}

extern "C" void kernel_launch(void* const* d_in, const int* in_sizes, int n_in,
                              void* d_out, int out_size, void* d_ws, size_t ws_size,
                              hipStream_t stream)
{
  const float* pos    = (const float*)d_in[0];
  const float* speed  = (const float*)d_in[1];
  const float* Wih_pe = (const float*)d_in[2];
  const float* Whh_pe = (const float*)d_in[3];
  const float* bih_pe = (const float*)d_in[4];
  const float* bhh_pe = (const float*)d_in[5];
  const float* Wih_se = (const float*)d_in[6];
  const float* Whh_se = (const float*)d_in[7];
  const float* bih_se = (const float*)d_in[8];
  const float* bhh_se = (const float*)d_in[9];
  const float* ln_g   = (const float*)d_in[10];
  const float* ln_b   = (const float*)d_in[11];
  const float* Wih_sd = (const float*)d_in[12];
  const float* Whh_sd = (const float*)d_in[13];
  const float* bih_sd = (const float*)d_in[14];
  const float* bhh_sd = (const float*)d_in[15];
  const float* Wih_pd = (const float*)d_in[16];
  const float* Whh_pd = (const float*)d_in[17];
  const float* bih_pd = (const float*)d_in[18];
  const float* bhh_pd = (const float*)d_in[19];
  const float* Wfc    = (const float*)d_in[20];
  const float* bfc    = (const float*)d_in[21];

  traj_kernel<<<BATCH/M, NTH, 0, stream>>>(
      pos, speed, Wih_pe, Whh_pe, bih_pe, bhh_pe,
      Wih_se, Whh_se, bih_se, bhh_se, ln_g, ln_b,
      Wih_sd, Whh_sd, bih_sd, bhh_sd, Wih_pd, Whh_pd, bih_pd, bhh_pd,
      Wfc, bfc, (float*)d_out);
}